// Round 7
// baseline (456.179 us; speedup 1.0000x reference)
//
#include <hip/hip_runtime.h>
#include <hip/hip_bf16.h>

#define DEV static __device__ __forceinline__

typedef __attribute__((ext_vector_type(8))) short s16x8;
typedef __attribute__((ext_vector_type(16))) float f32x16;
typedef __attribute__((ext_vector_type(4))) unsigned u32x4;

DEV float bf2f(short s) {
    unsigned u = ((unsigned)(unsigned short)s) << 16;
    union { unsigned u; float f; } c; c.u = u; return c.f;
}
DEV short f2bf(float f) {
    union { float f; unsigned u; } c; c.f = f;
    unsigned u = c.u;
    unsigned r = (u + 0x7FFFu + ((u >> 16) & 1u)) >> 16;
    return (short)r;
}

DEV f32x16 mfma(s16x8 a, s16x8 b, f32x16 c) {
    return __builtin_amdgcn_mfma_f32_32x32x16_bf16(a, b, c, 0, 0, 0);
}

// pack 2 fp32 -> 2 bf16 (RNE) in one u32 (lo = first arg)
DEV unsigned cvtpk(float lo, float hi) {
    unsigned r;
    asm("v_cvt_pk_bf16_f32 %0, %1, %2" : "=v"(r) : "v"(lo), "v"(hi));
    return r;
}
// a' = [a_lanes0-31 | b_lanes0-31], b' = [a_lanes32-63 | b_lanes32-63]
DEV void pl32swap(unsigned& a, unsigned& b) {
    asm volatile("v_permlane32_swap_b32 %0, %1" : "+v"(a), "+v"(b));
}

// ------------------------------------------------------- fp32 -> bf16 convert
__global__ void cvt_f32_bf16(const float* __restrict__ src,
                             short* __restrict__ dst, int n) {
    int i = (blockIdx.x * blockDim.x + threadIdx.x) * 4;
    if (i >= n) return;
    float4 v = *(const float4*)(src + i);
    short4 o;
    o.x = f2bf(v.x); o.y = f2bf(v.y); o.z = f2bf(v.z); o.w = f2bf(v.w);
    *(short4*)(dst + i) = o;
}

// ------------------------------------------------------- rotary table
// tab[n][f] = (cos(n*invfreq_f), sin(n*invfreq_f)), n<2048, f<32. 512 KB.
__global__ void rotab(float2* __restrict__ tab) {
    int idx = blockIdx.x * 256 + threadIdx.x;  // 65536 entries
    int n = idx >> 5, f = idx & 31;
    float inv = expf(-0.2878231366f * (float)f);  // 10000^(-f/32)
    float a = (float)n * inv;
    tab[idx] = make_float2(cosf(a), sinf(a));
}

// ------------------------------------------- transpose fp32 (RxC) -> bf16 (CxR)
__global__ void ktransf(const float* __restrict__ src, short* __restrict__ dst,
                        int R, int C) {
    __shared__ __align__(16) short t[32][33];
    int tx = threadIdx.x & 31, ty = threadIdx.x >> 5;  // ty 0..7
    int r0 = blockIdx.y * 32, c0 = blockIdx.x * 32;
    for (int i = 0; i < 32; i += 8)
        t[ty + i][tx] = f2bf(src[(size_t)(r0 + ty + i) * C + c0 + tx]);
    __syncthreads();
    for (int i = 0; i < 32; i += 8)
        dst[(size_t)(c0 + ty + i) * R + r0 + tx] = t[tx][ty + i];
}

// ---------------------------------------------------------------- QKV GEMM
// X (8192 x 512, bf16) @ W (512 x 1536) with W transposed WT (1536 x 512, bf16)
// Epilogue: q scale + rotary (table) -> qws/kws (b,h,n,d); v -> vt (b,h,d,n).
__global__ __launch_bounds__(256) void gemm_qkv(
    const short* __restrict__ X, const short* __restrict__ WT,
    const float2* __restrict__ rtab,
    short* __restrict__ qws, short* __restrict__ kws, short* __restrict__ vt) {
    int wave = threadIdx.x >> 6, lane = threadIdx.x & 63;
    int l31 = lane & 31, lh = lane >> 5;
    int mw = blockIdx.x * 128 + (wave >> 1) * 64;
    int nw = blockIdx.y * 128 + (wave & 1) * 64;
    f32x16 acc[2][2] = {};
    const short* ap = X + (size_t)(mw + l31) * 512 + lh * 8;
    const short* bp = WT + (size_t)(nw + l31) * 512 + lh * 8;
#pragma unroll 4
    for (int k = 0; k < 512; k += 16) {
        s16x8 a0 = *(const s16x8*)(ap + k);
        s16x8 a1 = *(const s16x8*)(ap + 32 * 512 + k);
        s16x8 b0 = *(const s16x8*)(bp + k);
        s16x8 b1 = *(const s16x8*)(bp + 32 * 512 + k);
        acc[0][0] = mfma(a0, b0, acc[0][0]);
        acc[0][1] = mfma(a0, b1, acc[0][1]);
        acc[1][0] = mfma(a1, b0, acc[1][0]);
        acc[1][1] = mfma(a1, b1, acc[1][1]);
    }
#pragma unroll
    for (int ib = 0; ib < 2; ib++)
#pragma unroll
        for (int jb = 0; jb < 2; jb++) {
            int col = nw + jb * 32 + l31;
            int t = col >> 9;          // 0=q 1=k 2=v (uniform across wave)
            int cid = col & 511;
            int h = cid >> 6, d = cid & 63;
#pragma unroll
            for (int r = 0; r < 16; r++) {
                int row = (r & 3) + 8 * (r >> 2) + 4 * lh;
                int gm = mw + ib * 32 + row;
                int b = gm >> 11, n = gm & 2047;
                float v = acc[ib][jb][r];
                if (t == 0) v *= 0.125f;  // DIM_HEAD^-0.5
                if (t < 2) {
                    float pv = __shfl_xor(v, 1);
                    float2 cs = rtab[n * 32 + (d >> 1)];
                    float o = (d & 1) ? (v * cs.x + pv * cs.y)
                                      : (v * cs.x - pv * cs.y);
                    short* dst = (t == 0) ? qws : kws;
                    dst[((size_t)(b * 8 + h) * 2048 + n) * 64 + d] = f2bf(o);
                } else {
                    vt[((size_t)(b * 8 + h) * 64 + d) * 2048 + n] = f2bf(v);
                }
            }
        }
}

// ---------------------------------------------------------------- attention
// Per (b,h): attention over N=2048, D=64, pos_bias (fp32) added.
// No-max softmax (scores+bias bounded ~8.5 -> exp safe in fp32).
//
// R5/R6 exonerated memory (FETCH 193->78MB, all L2-resident; time flat at
// ~170us). The stall is the per-tile in-wave chain: LDS P roundtrip +
// ~600 VALU (f2bf/addressing/16-reg lsum shuffles).
// R7 = swapped QK^T + fully in-register P (guide T12):
//   s = mfma(K, Q): lane (l31,lh) holds S[key=kb+cr(r,lh)][q=q0+l31],
//   cr(r,lh) = (r&3)+8*(r>>2)+4*lh.  P-row is lane-local in q.
//   - bias: 8 float4 loads/lane at [q0+l31][kb+8g+4lh] matches cr exactly
//   - P -> PV A-frag: 16 cvt_pk_bf16 + 8 permlane32_swap:
//       swap(x_{2c}, x_{2c+1}) -> frag words w0,w2 ; swap(y...) -> w1,w3
//   - lsum: 4 regs, ONE shfl_xor(32) at the end (was 16 regs + 96 shuffles)
//   - zero LDS, zero bank conflicts, no lgkm waits, no DMA/vmcnt hacks
// XCD=head block mapping kept from R6 (L2 locality win: FETCH 78MB).
__global__ __launch_bounds__(64) void attn(
    const short* __restrict__ qws, const short* __restrict__ kws,
    const short* __restrict__ vt, const float* __restrict__ bias,
    short* __restrict__ ows) {
    int lane = threadIdx.x;
    int l31 = lane & 31, lh = lane >> 5;
    int bid = blockIdx.x;
    int h = bid & 7;            // XCD-local head
    int b = (bid >> 3) & 3;
    int q0 = (bid >> 5) * 32;
    int bh = b * 8 + h;

    const short* qp = qws + ((size_t)bh * 2048 + q0 + l31) * 64 + lh * 8;
    s16x8 qf[4];
#pragma unroll
    for (int c = 0; c < 4; c++) qf[c] = *(const s16x8*)(qp + c * 16);

    f32x16 oa[2] = {};
    float ls0 = 0.f, ls1 = 0.f, ls2 = 0.f, ls3 = 0.f;

    const float* browp = bias + ((size_t)h * 2048 + q0 + l31) * 2048;
    const short* kbase = kws + ((size_t)bh * 2048 + l31) * 64 + lh * 8;
    const short* vbase = vt + ((size_t)bh * 64 + l31) * 2048 + lh * 8;

    for (int kt = 0; kt < 32; kt++) {
        int kb = kt * 64;
        // ---- K fragment loads (lane = key row; B-op... now A-op of swapped QK)
        const short* kp = kbase + (size_t)kb * 64;
        s16x8 k0[4], k1[4];
#pragma unroll
        for (int c = 0; c < 4; c++) {
            k0[c] = *(const s16x8*)(kp + c * 16);
            k1[c] = *(const s16x8*)(kp + 32 * 64 + c * 16);
        }
        // ---- bias: 2x4 float4 per lane, row q0+l31, cols kb+8g+4lh(+32)
        float bae[16], bbe[16];
#pragma unroll
        for (int g = 0; g < 4; g++) {
            float4 ta = *(const float4*)(browp + kb + 8 * g + 4 * lh);
            float4 tb = *(const float4*)(browp + kb + 32 + 8 * g + 4 * lh);
            bae[4 * g + 0] = ta.x; bae[4 * g + 1] = ta.y;
            bae[4 * g + 2] = ta.z; bae[4 * g + 3] = ta.w;
            bbe[4 * g + 0] = tb.x; bbe[4 * g + 1] = tb.y;
            bbe[4 * g + 2] = tb.z; bbe[4 * g + 3] = tb.w;
        }
        // ---- swapped QK^T: S^T[key][q]
        f32x16 s0 = {}, s1 = {};
#pragma unroll
        for (int c = 0; c < 4; c++) {
            s0 = mfma(k0[c], qf[c], s0);
            s1 = mfma(k1[c], qf[c], s1);
        }
        // ---- V fragment loads issued while QK executes
        const short* vp = vbase + kb;
        s16x8 v0f[4], v1f[4];
#pragma unroll
        for (int c = 0; c < 4; c++) {
            v0f[c] = *(const s16x8*)(vp + c * 16);
            v1f[c] = *(const s16x8*)(vp + (size_t)32 * 2048 + c * 16);
        }
        // ---- exp(S + bias), lane-local rows; 4-way partial sums
        float p0[16], p1[16];
#pragma unroll
        for (int r = 0; r < 16; r++) {
            float e0 = __expf(s0[r] + bae[r]);
            float e1 = __expf(s1[r] + bbe[r]);
            p0[r] = e0; p1[r] = e1;
            if ((r & 3) == 0) ls0 += e0 + e1;
            else if ((r & 3) == 1) ls1 += e0 + e1;
            else if ((r & 3) == 2) ls2 += e0 + e1;
            else ls3 += e0 + e1;
        }
        // ---- pack P into A-frags (cvt_pk + permlane32_swap) and PV
#pragma unroll
        for (int c = 0; c < 4; c++) {
            const float* ps = (c < 2) ? p0 : p1;
            int gb = (c & 1) * 2;  // groups gb, gb+1
            unsigned x0 = cvtpk(ps[4 * gb + 0], ps[4 * gb + 1]);
            unsigned x1 = cvtpk(ps[4 * (gb + 1) + 0], ps[4 * (gb + 1) + 1]);
            unsigned y0 = cvtpk(ps[4 * gb + 2], ps[4 * gb + 3]);
            unsigned y1 = cvtpk(ps[4 * (gb + 1) + 2], ps[4 * (gb + 1) + 3]);
            pl32swap(x0, x1);  // x0 = w0 (keys +0,1), x1 = w2 (keys +4,5)
            pl32swap(y0, y1);  // y0 = w1 (keys +2,3), y1 = w3 (keys +6,7)
            u32x4 uw = {x0, y0, x1, y1};
            union { u32x4 u; s16x8 s; } pa; pa.u = uw;
            oa[0] = mfma(pa.s, v0f[c], oa[0]);
            oa[1] = mfma(pa.s, v1f[c], oa[1]);
        }
    }
    // ---- epilogue: one cross-half reduce; inv broadcast by q-row
    float lsum = (ls0 + ls1) + (ls2 + ls3);
    lsum += __shfl_xor(lsum, 32);
    float inv = 1.f / lsum;  // inv for q = q0 + l31 (both halves hold it)
#pragma unroll
    for (int r = 0; r < 16; r++) {
        int cr = (r & 3) + 8 * (r >> 2) + 4 * lh;  // output q-row
        float invr = __shfl(inv, cr);
        size_t o0 = ((size_t)(b * 2048 + q0 + cr) * 8 + h) * 64;
        ows[o0 + l31] = f2bf(oa[0][r] * invr);
        ows[o0 + 32 + l31] = f2bf(oa[1][r] * invr);
    }
}

// ---------------------------------------------------------------- out GEMM
// O (8192 x 512, bf16) @ W_out (512 x 512) with WT (512 x 512, bf16).
// Output written as FP32 (reference output dtype is float32).
__global__ __launch_bounds__(256) void gemm_out(
    const short* __restrict__ O, const short* __restrict__ WT,
    float* __restrict__ out) {
    int wave = threadIdx.x >> 6, lane = threadIdx.x & 63;
    int l31 = lane & 31, lh = lane >> 5;
    int m0 = blockIdx.x * 128 + (wave >> 1) * 64;
    int n0 = blockIdx.y * 128 + (wave & 1) * 64;
    f32x16 acc[2][2] = {};
    const short* ap = O + (size_t)(m0 + l31) * 512 + lh * 8;
    const short* bp = WT + (size_t)(n0 + l31) * 512 + lh * 8;
#pragma unroll 4
    for (int k = 0; k < 512; k += 16) {
        s16x8 a0 = *(const s16x8*)(ap + k);
        s16x8 a1 = *(const s16x8*)(ap + 32 * 512 + k);
        s16x8 b0 = *(const s16x8*)(bp + k);
        s16x8 b1 = *(const s16x8*)(bp + 32 * 512 + k);
        acc[0][0] = mfma(a0, b0, acc[0][0]);
        acc[0][1] = mfma(a0, b1, acc[0][1]);
        acc[1][0] = mfma(a1, b0, acc[1][0]);
        acc[1][1] = mfma(a1, b1, acc[1][1]);
    }
#pragma unroll
    for (int ib = 0; ib < 2; ib++)
#pragma unroll
        for (int jb = 0; jb < 2; jb++)
#pragma unroll
            for (int r = 0; r < 16; r++) {
                int row = (r & 3) + 8 * (r >> 2) + 4 * lh;
                out[(size_t)(m0 + ib * 32 + row) * 512 + n0 + jb * 32 + l31] =
                    acc[ib][jb][r];
            }
}

// ---------------------------------------------------------------- launch
extern "C" void kernel_launch(void* const* d_in, const int* in_sizes, int n_in,
                              void* d_out, int out_size, void* d_ws,
                              size_t ws_size, hipStream_t stream) {
    const float* x    = (const float*)d_in[0];  // (4,2048,512) fp32
    const float* bias = (const float*)d_in[1];  // (8,2048,2048) fp32
    const float* wqkv = (const float*)d_in[2];  // (512,1536) fp32
    const float* wout = (const float*)d_in[3];  // (512,512) fp32
    float* out = (float*)d_out;                 // (4,2048,512) fp32

    char* ws = (char*)d_ws;
    short* xbf   = (short*)ws;                         // 4M shorts (8 MB)
    short* wqkvT = xbf + 4194304;                      // 1536*512
    short* woutT = wqkvT + 786432;                     // 512*512
    short* qws   = woutT + 262144;                     // 4*8*2048*64
    short* kws   = qws + 4194304;
    short* vt    = kws + 4194304;
    short* ows   = vt + 4194304;
    float2* rtab = (float2*)(ows + 4194304);           // 65536 float2 (512 KB)

    cvt_f32_bf16<<<4096, 256, 0, stream>>>(x, xbf, 4194304);
    rotab<<<256, 256, 0, stream>>>(rtab);
    ktransf<<<dim3(1536 / 32, 512 / 32), 256, 0, stream>>>(wqkv, wqkvT, 512, 1536);
    ktransf<<<dim3(512 / 32, 512 / 32), 256, 0, stream>>>(wout, woutT, 512, 512);
    gemm_qkv<<<dim3(64, 12), 256, 0, stream>>>(xbf, wqkvT, rtab, qws, kws, vt);
    attn<<<2048, 64, 0, stream>>>(qws, kws, vt, bias, ows);
    gemm_out<<<dim3(64, 4), 256, 0, stream>>>(ows, woutT, out);
}